// Round 1
// baseline (230.332 us; speedup 1.0000x reference)
//
#include <hip/hip_runtime.h>
#include <hip/hip_bf16.h>

#define B_    8
#define N_    1024
#define C_    512
#define H_    4
#define HD_   128
#define BN_   (B_ * N_)      // 8192
#define QKVC_ 1536
#define SCALE_ 0.08838834764831845f  // 128^-0.5

typedef __bf16 bf16;
typedef __bf16 bf16x8 __attribute__((ext_vector_type(8)));
typedef float  floatx4 __attribute__((ext_vector_type(4)));

// ---------------------------------------------------------------------------
// Kernel 1: qkv = x @ w_qkv^T, fp32 inputs -> bf16 output [BN, 1536]
// C[m][n] = sum_k A[m][k] * W[n][k]
// ---------------------------------------------------------------------------
__global__ __launch_bounds__(256) void qkv_gemm(const float* __restrict__ A,
                                                const float* __restrict__ W,
                                                bf16* __restrict__ Cout) {
    const int m0 = blockIdx.x * 64;
    const int n0 = blockIdx.y * 64;
    const int t = threadIdx.x;
    const int wave = t >> 6, lane = t & 63;
    const int quad = lane >> 4, l16 = lane & 15;

    __shared__ bf16 At[64][40];   // stride 40 shorts = 80B (16B aligned rows)
    __shared__ bf16 Bt[64][40];

    floatx4 acc[4] = {};

    const int lr = t >> 2;            // 0..63
    const int lc = (t & 3) * 8;       // 0,8,16,24

    for (int k0 = 0; k0 < 512; k0 += 32) {
        __syncthreads();
        {
            const float* src = A + (size_t)(m0 + lr) * 512 + k0 + lc;
            float4 f0 = *(const float4*)(src);
            float4 f1 = *(const float4*)(src + 4);
            bf16x8 v;
            v[0] = (bf16)f0.x; v[1] = (bf16)f0.y; v[2] = (bf16)f0.z; v[3] = (bf16)f0.w;
            v[4] = (bf16)f1.x; v[5] = (bf16)f1.y; v[6] = (bf16)f1.z; v[7] = (bf16)f1.w;
            *(bf16x8*)&At[lr][lc] = v;

            const float* srcB = W + (size_t)(n0 + lr) * 512 + k0 + lc;
            float4 g0 = *(const float4*)(srcB);
            float4 g1 = *(const float4*)(srcB + 4);
            bf16x8 w;
            w[0] = (bf16)g0.x; w[1] = (bf16)g0.y; w[2] = (bf16)g0.z; w[3] = (bf16)g0.w;
            w[4] = (bf16)g1.x; w[5] = (bf16)g1.y; w[6] = (bf16)g1.z; w[7] = (bf16)g1.w;
            *(bf16x8*)&Bt[lr][lc] = w;
        }
        __syncthreads();

        bf16x8 a = *(const bf16x8*)&At[wave * 16 + l16][quad * 8];
#pragma unroll
        for (int nt = 0; nt < 4; nt++) {
            bf16x8 b = *(const bf16x8*)&Bt[nt * 16 + l16][quad * 8];
            acc[nt] = __builtin_amdgcn_mfma_f32_16x16x32_bf16(a, b, acc[nt], 0, 0, 0);
        }
    }

#pragma unroll
    for (int nt = 0; nt < 4; nt++) {
#pragma unroll
        for (int r = 0; r < 4; r++) {
            int row = m0 + wave * 16 + quad * 4 + r;
            int col = n0 + nt * 16 + l16;
            Cout[(size_t)row * QKVC_ + col] = (bf16)acc[nt][r];
        }
    }
}

// ---------------------------------------------------------------------------
// Kernel 2: fused CIM flash attention.
// Mixed logits: S'_i[n,m] = sum_k Q'_i[n][k] * Kcat[m][k], k in [0,512),
// Q'_i built from q with per-head scale SCALE*M[i,h] folded in at load.
// Online softmax, O_i += P @ V_i.  Output bf16 [BN, C] (head-major cols).
// ---------------------------------------------------------------------------
__global__ __launch_bounds__(256) void flash_attn(const bf16* __restrict__ qkv,
                                                  const float* __restrict__ w_main,
                                                  const float* __restrict__ w_rest,
                                                  bf16* __restrict__ attn_out) {
    const int b = blockIdx.z;
    const int head = blockIdx.y;
    const int n0 = blockIdx.x * 64;
    const int t = threadIdx.x;
    const int wave = t >> 6, lane = t & 63;
    const int quad = lane >> 4, l16 = lane & 15;

    // mix coefficients: M[head][j], SCALE folded in
    float qs[H_];
#pragma unroll
    for (int j = 0; j < H_; j++) {
        float mij = (j == head) ? w_main[head]
                                : w_rest[head * (H_ - 1) + (j - (j > head ? 1 : 0))];
        qs[j] = mij * SCALE_;
    }

    __shared__ bf16 Kt[32][520];       // K-tile [32 rows][512], pad 8 (rows 16B aligned)
    __shared__ bf16 Vt[128][40];       // V-tile transposed [d][row], pad 8
    __shared__ bf16 Pb[4][16][40];     // per-wave P staging [16 rows][32], pad 8

    // Load Q' fragments once (A-operand layout: m=l16, k=quad*8+j)
    bf16x8 qf[16];
    const int qrow = n0 + wave * 16 + l16;
    const bf16* qbase = qkv + (size_t)(b * N_ + qrow) * QKVC_;
#pragma unroll
    for (int kk = 0; kk < 16; kk++) {
        int kg = kk * 32 + quad * 8;
        bf16x8 v = *(const bf16x8*)(qbase + kg);
        float sc = qs[kg >> 7];
        bf16x8 q;
#pragma unroll
        for (int j = 0; j < 8; j++) q[j] = (bf16)((float)v[j] * sc);
        qf[kk] = q;
    }

    floatx4 o[8] = {};
    float mrow[4] = {-1e30f, -1e30f, -1e30f, -1e30f};
    float lrow[4] = {0.f, 0.f, 0.f, 0.f};

    const bf16* kvbase = qkv + (size_t)(b * N_) * QKVC_;

    for (int m0 = 0; m0 < N_; m0 += 32) {
        __syncthreads();
        // K tile: 32x512 bf16, fully coalesced 16B chunks
#pragma unroll
        for (int i = 0; i < 8; i++) {
            int cid = i * 256 + t;
            int r = cid >> 6, c8 = (cid & 63) * 8;
            *(bf16x8*)&Kt[r][c8] =
                *(const bf16x8*)(kvbase + (size_t)(m0 + r) * QKVC_ + 512 + c8);
        }
        // V tile transposed: thread reads 32B of one v-row, scatters to Vt[d][r]
        {
            int r = t & 31, d0 = (t >> 5) * 16;
            const bf16* vsrc =
                kvbase + (size_t)(m0 + r) * QKVC_ + 1024 + head * HD_ + d0;
            bf16x8 v0 = *(const bf16x8*)(vsrc);
            bf16x8 v1 = *(const bf16x8*)(vsrc + 8);
#pragma unroll
            for (int j = 0; j < 8; j++) {
                Vt[d0 + j][r] = v0[j];
                Vt[d0 + 8 + j][r] = v1[j];
            }
        }
        __syncthreads();

        // Scores: S[16 x 32] = Q'[16 x 512] @ Kcat^T
        floatx4 s[2] = {};
#pragma unroll
        for (int kk = 0; kk < 16; kk++) {
#pragma unroll
            for (int nt = 0; nt < 2; nt++) {
                bf16x8 kb = *(const bf16x8*)&Kt[nt * 16 + l16][kk * 32 + quad * 8];
                s[nt] = __builtin_amdgcn_mfma_f32_16x16x32_bf16(qf[kk], kb, s[nt], 0, 0, 0);
            }
        }

        // Online softmax (row = quad*4 + r, cols spread over 16 lanes x 2 nt)
#pragma unroll
        for (int r = 0; r < 4; r++) {
            float mx = fmaxf(s[0][r], s[1][r]);
#pragma unroll
            for (int off = 1; off < 16; off <<= 1) mx = fmaxf(mx, __shfl_xor(mx, off));
            float mnew = fmaxf(mrow[r], mx);
            float alpha = __expf(mrow[r] - mnew);
            mrow[r] = mnew;
            float p0 = __expf(s[0][r] - mnew);
            float p1 = __expf(s[1][r] - mnew);
            s[0][r] = p0;
            s[1][r] = p1;
            float sm = p0 + p1;
#pragma unroll
            for (int off = 1; off < 16; off <<= 1) sm += __shfl_xor(sm, off);
            lrow[r] = lrow[r] * alpha + sm;
#pragma unroll
            for (int nt = 0; nt < 8; nt++) o[nt][r] *= alpha;
        }

        // P: D-layout -> LDS -> A-layout
#pragma unroll
        for (int nt = 0; nt < 2; nt++)
#pragma unroll
            for (int r = 0; r < 4; r++)
                Pb[wave][quad * 4 + r][nt * 16 + l16] = (bf16)s[nt][r];
        __syncthreads();

        bf16x8 pf = *(const bf16x8*)&Pb[wave][l16][quad * 8];
#pragma unroll
        for (int nt = 0; nt < 8; nt++) {
            bf16x8 vf = *(const bf16x8*)&Vt[nt * 16 + l16][quad * 8];
            o[nt] = __builtin_amdgcn_mfma_f32_16x16x32_bf16(pf, vf, o[nt], 0, 0, 0);
        }
    }

    // Epilogue: normalize and store bf16 [b, n, head*128 + d]
#pragma unroll
    for (int r = 0; r < 4; r++) {
        float inv = 1.0f / lrow[r];
        int row = n0 + wave * 16 + quad * 4 + r;
        bf16* dst = attn_out + (size_t)(b * N_ + row) * C_ + head * HD_;
#pragma unroll
        for (int nt = 0; nt < 8; nt++)
            dst[nt * 16 + l16] = (bf16)(o[nt][r] * inv);
    }
}

// ---------------------------------------------------------------------------
// Kernel 3: out = attn_out @ w_proj^T + b_proj, bf16 A, fp32 W -> fp32 out
// ---------------------------------------------------------------------------
__global__ __launch_bounds__(256) void proj_gemm(const bf16* __restrict__ A,
                                                 const float* __restrict__ W,
                                                 const float* __restrict__ Bp,
                                                 float* __restrict__ Cout) {
    const int m0 = blockIdx.x * 64;
    const int n0 = blockIdx.y * 64;
    const int t = threadIdx.x;
    const int wave = t >> 6, lane = t & 63;
    const int quad = lane >> 4, l16 = lane & 15;

    __shared__ bf16 At[64][40];
    __shared__ bf16 Bt[64][40];

    floatx4 acc[4] = {};

    const int lr = t >> 2;
    const int lc = (t & 3) * 8;

    for (int k0 = 0; k0 < 512; k0 += 32) {
        __syncthreads();
        {
            *(bf16x8*)&At[lr][lc] =
                *(const bf16x8*)(A + (size_t)(m0 + lr) * 512 + k0 + lc);

            const float* srcB = W + (size_t)(n0 + lr) * 512 + k0 + lc;
            float4 g0 = *(const float4*)(srcB);
            float4 g1 = *(const float4*)(srcB + 4);
            bf16x8 w;
            w[0] = (bf16)g0.x; w[1] = (bf16)g0.y; w[2] = (bf16)g0.z; w[3] = (bf16)g0.w;
            w[4] = (bf16)g1.x; w[5] = (bf16)g1.y; w[6] = (bf16)g1.z; w[7] = (bf16)g1.w;
            *(bf16x8*)&Bt[lr][lc] = w;
        }
        __syncthreads();

        bf16x8 a = *(const bf16x8*)&At[wave * 16 + l16][quad * 8];
#pragma unroll
        for (int nt = 0; nt < 4; nt++) {
            bf16x8 b = *(const bf16x8*)&Bt[nt * 16 + l16][quad * 8];
            acc[nt] = __builtin_amdgcn_mfma_f32_16x16x32_bf16(a, b, acc[nt], 0, 0, 0);
        }
    }

#pragma unroll
    for (int nt = 0; nt < 4; nt++) {
        int col = n0 + nt * 16 + l16;
        float bias = Bp[col];
#pragma unroll
        for (int r = 0; r < 4; r++) {
            int row = m0 + wave * 16 + quad * 4 + r;
            Cout[(size_t)row * C_ + col] = acc[nt][r] + bias;
        }
    }
}

// ---------------------------------------------------------------------------
extern "C" void kernel_launch(void* const* d_in, const int* in_sizes, int n_in,
                              void* d_out, int out_size, void* d_ws, size_t ws_size,
                              hipStream_t stream) {
    const float* x      = (const float*)d_in[0];
    const float* w_qkv  = (const float*)d_in[1];
    const float* w_proj = (const float*)d_in[2];
    const float* b_proj = (const float*)d_in[3];
    const float* w_main = (const float*)d_in[4];
    const float* w_rest = (const float*)d_in[5];
    float* out = (float*)d_out;

    bf16* qkv = (bf16*)d_ws;                              // [8192, 1536] bf16
    bf16* attn_out = qkv + (size_t)BN_ * QKVC_;           // [8192, 512]  bf16

    qkv_gemm<<<dim3(BN_ / 64, QKVC_ / 64), 256, 0, stream>>>(x, w_qkv, qkv);
    flash_attn<<<dim3(N_ / 64, H_, B_), 256, 0, stream>>>(qkv, w_main, w_rest, attn_out);
    proj_gemm<<<dim3(BN_ / 64, C_ / 64), 256, 0, stream>>>(attn_out, w_proj, b_proj, out);
}

// Round 2
// 213.150 us; speedup vs baseline: 1.0806x; 1.0806x over previous
//
#include <hip/hip_runtime.h>
#include <hip/hip_bf16.h>

#define B_    8
#define N_    1024
#define C_    512
#define H_    4
#define HD_   128
#define BN_   (B_ * N_)      // 8192
#define QKVC_ 1536
#define SCALE_ 0.08838834764831845f  // 128^-0.5

typedef __bf16 bf16;
typedef __bf16 bf16x8 __attribute__((ext_vector_type(8)));
typedef float  floatx4 __attribute__((ext_vector_type(4)));

__device__ __forceinline__ void gload_lds16(const bf16* g, bf16* l) {
    __builtin_amdgcn_global_load_lds(
        (const __attribute__((address_space(1))) void*)g,
        (__attribute__((address_space(3))) void*)l, 16, 0, 0);
}

// ---------------------------------------------------------------------------
// Kernel 0: fp32 -> bf16 conversion for x, w_qkv, w_proj.
// Branch boundaries are block-aligned (2048 / 384 / 128 blocks).
// ---------------------------------------------------------------------------
__global__ __launch_bounds__(256) void cvt_bf16(const float* __restrict__ x,  bf16* __restrict__ xb,
                                                const float* __restrict__ wq, bf16* __restrict__ wqb,
                                                const float* __restrict__ wp, bf16* __restrict__ wpb) {
    int id = blockIdx.x * 256 + threadIdx.x;
    const float* s; bf16* d; int off;
    if (id < 524288)      { s = x;  d = xb;  off = id; }
    else if (id < 622592) { s = wq; d = wqb; off = id - 524288; }
    else                  { s = wp; d = wpb; off = id - 622592; }
    const float4* sp = (const float4*)s + (size_t)off * 2;
    float4 f0 = sp[0], f1 = sp[1];
    bf16x8 v;
    v[0] = (bf16)f0.x; v[1] = (bf16)f0.y; v[2] = (bf16)f0.z; v[3] = (bf16)f0.w;
    v[4] = (bf16)f1.x; v[5] = (bf16)f1.y; v[6] = (bf16)f1.z; v[7] = (bf16)f1.w;
    ((bf16x8*)d)[off] = v;
}

// ---------------------------------------------------------------------------
// m97-class GEMM: C[m][n] = sum_k A[m][k]*Bw[n][k] (+bias), bf16 in.
// Tile 128 x TN, BK=64.  LDS tiles [rows][64] unpadded, XOR chunk swizzle:
//   LDS(r, chunk p) holds global chunk c = p ^ (r&7)
// -> global_load_lds-compatible (contiguous lane order: lane i loads global
//    chunk (i&7)^(i>>3) of row r0+i/8) AND conflict-free ds_read_b128
//    (phase lanes l16=0..7 read banks 4*((kc^l16)&7)..+3 -> all 32 banks).
// ---------------------------------------------------------------------------
template<int TN, int NOUT, bool F32OUT>
__global__ __launch_bounds__(256) void gemm_bt(const bf16* __restrict__ A,
                                               const bf16* __restrict__ Bw,
                                               const float* __restrict__ bias,
                                               void* __restrict__ Cout) {
    constexpr int NT = TN / 32;
    const int t = threadIdx.x;
    const int wave = t >> 6, lane = t & 63;
    const int quad = lane >> 4, l16 = lane & 15;
    const int ro = lane >> 3;            // row within 8-row staging group
    const int ch = (lane & 7) ^ ro;      // swizzled source chunk

    const int m_base = blockIdx.x * 128;
    const int n_base = blockIdx.y * TN;
    const int wave_r = (wave & 1) * 64;
    const int wave_c = (wave >> 1) * (TN / 2);

    __shared__ bf16 As[128 * 64];
    __shared__ bf16 Bs[TN * 64];

    floatx4 acc[4][NT] = {};

    for (int k0 = 0; k0 < 512; k0 += 64) {
        __syncthreads();
#pragma unroll
        for (int j = 0; j < 4; j++) {
            int r0 = (wave * 4 + j) * 8;
            gload_lds16(A + (size_t)(m_base + r0 + ro) * 512 + k0 + ch * 8,
                        As + r0 * 64);
        }
#pragma unroll
        for (int j = 0; j < TN / 32; j++) {
            int r0 = (wave * (TN / 32) + j) * 8;
            gload_lds16(Bw + (size_t)(n_base + r0 + ro) * 512 + k0 + ch * 8,
                        Bs + r0 * 64);
        }
        __syncthreads();

#pragma unroll
        for (int kk = 0; kk < 2; kk++) {
            const int kc = kk * 4 + quad;
            bf16x8 af[4], bfr[NT];
#pragma unroll
            for (int mt = 0; mt < 4; mt++) {
                int r = wave_r + mt * 16 + l16;
                af[mt] = *(const bf16x8*)&As[r * 64 + ((kc ^ (r & 7)) * 8)];
            }
#pragma unroll
            for (int nt = 0; nt < NT; nt++) {
                int r = wave_c + nt * 16 + l16;
                bfr[nt] = *(const bf16x8*)&Bs[r * 64 + ((kc ^ (r & 7)) * 8)];
            }
#pragma unroll
            for (int mt = 0; mt < 4; mt++)
#pragma unroll
                for (int nt = 0; nt < NT; nt++)
                    acc[mt][nt] = __builtin_amdgcn_mfma_f32_16x16x32_bf16(
                        af[mt], bfr[nt], acc[mt][nt], 0, 0, 0);
        }
    }

#pragma unroll
    for (int nt = 0; nt < NT; nt++) {
        int col = n_base + wave_c + nt * 16 + l16;
        float bi = 0.f;
        if constexpr (F32OUT) bi = bias[col];
#pragma unroll
        for (int mt = 0; mt < 4; mt++) {
#pragma unroll
            for (int r = 0; r < 4; r++) {
                int row = m_base + wave_r + mt * 16 + quad * 4 + r;
                if constexpr (F32OUT)
                    ((float*)Cout)[(size_t)row * NOUT + col] = acc[mt][nt][r] + bi;
                else
                    ((bf16*)Cout)[(size_t)row * NOUT + col] = (bf16)acc[mt][nt][r];
            }
        }
    }
}

// ---------------------------------------------------------------------------
// Fused CIM flash attention (unchanged math; barrier #3 removed — Pb is
// wave-private, compiler lgkmcnt covers the within-wave LDS RAW).
// ---------------------------------------------------------------------------
__global__ __launch_bounds__(256) void flash_attn(const bf16* __restrict__ qkv,
                                                  const float* __restrict__ w_main,
                                                  const float* __restrict__ w_rest,
                                                  bf16* __restrict__ attn_out) {
    const int b = blockIdx.z;
    const int head = blockIdx.y;
    const int n0 = blockIdx.x * 64;
    const int t = threadIdx.x;
    const int wave = t >> 6, lane = t & 63;
    const int quad = lane >> 4, l16 = lane & 15;

    float qs[H_];
#pragma unroll
    for (int j = 0; j < H_; j++) {
        float mij = (j == head) ? w_main[head]
                                : w_rest[head * (H_ - 1) + (j - (j > head ? 1 : 0))];
        qs[j] = mij * SCALE_;
    }

    __shared__ bf16 Kt[32][520];       // 520*2 B rows: 16B aligned, 260 dw ≡ 4 mod 32
    __shared__ bf16 Vt[128][40];       // 20 dw stride: b128-read conflict-free
    __shared__ bf16 Pb[4][16][40];     // per-wave P staging

    bf16x8 qf[16];
    const int qrow = n0 + wave * 16 + l16;
    const bf16* qbase = qkv + (size_t)(b * N_ + qrow) * QKVC_;
#pragma unroll
    for (int kk = 0; kk < 16; kk++) {
        int kg = kk * 32 + quad * 8;
        bf16x8 v = *(const bf16x8*)(qbase + kg);
        float sc = qs[kg >> 7];
        bf16x8 q;
#pragma unroll
        for (int j = 0; j < 8; j++) q[j] = (bf16)((float)v[j] * sc);
        qf[kk] = q;
    }

    floatx4 o[8] = {};
    float mrow[4] = {-1e30f, -1e30f, -1e30f, -1e30f};
    float lrow[4] = {0.f, 0.f, 0.f, 0.f};

    const bf16* kvbase = qkv + (size_t)(b * N_) * QKVC_;

    for (int m0 = 0; m0 < N_; m0 += 32) {
        __syncthreads();
#pragma unroll
        for (int i = 0; i < 8; i++) {
            int cid = i * 256 + t;
            int r = cid >> 6, c8 = (cid & 63) * 8;
            *(bf16x8*)&Kt[r][c8] =
                *(const bf16x8*)(kvbase + (size_t)(m0 + r) * QKVC_ + 512 + c8);
        }
        {
            int r = t & 31, d0 = (t >> 5) * 16;
            const bf16* vsrc =
                kvbase + (size_t)(m0 + r) * QKVC_ + 1024 + head * HD_ + d0;
            bf16x8 v0 = *(const bf16x8*)(vsrc);
            bf16x8 v1 = *(const bf16x8*)(vsrc + 8);
#pragma unroll
            for (int j = 0; j < 8; j++) {
                Vt[d0 + j][r] = v0[j];
                Vt[d0 + 8 + j][r] = v1[j];
            }
        }
        __syncthreads();

        floatx4 s[2] = {};
#pragma unroll
        for (int kk = 0; kk < 16; kk++) {
#pragma unroll
            for (int nt = 0; nt < 2; nt++) {
                bf16x8 kb = *(const bf16x8*)&Kt[nt * 16 + l16][kk * 32 + quad * 8];
                s[nt] = __builtin_amdgcn_mfma_f32_16x16x32_bf16(qf[kk], kb, s[nt], 0, 0, 0);
            }
        }

#pragma unroll
        for (int r = 0; r < 4; r++) {
            float mx = fmaxf(s[0][r], s[1][r]);
#pragma unroll
            for (int off = 1; off < 16; off <<= 1) mx = fmaxf(mx, __shfl_xor(mx, off));
            float mnew = fmaxf(mrow[r], mx);
            float alpha = __expf(mrow[r] - mnew);
            mrow[r] = mnew;
            float p0 = __expf(s[0][r] - mnew);
            float p1 = __expf(s[1][r] - mnew);
            s[0][r] = p0;
            s[1][r] = p1;
            float sm = p0 + p1;
#pragma unroll
            for (int off = 1; off < 16; off <<= 1) sm += __shfl_xor(sm, off);
            lrow[r] = lrow[r] * alpha + sm;
#pragma unroll
            for (int nt = 0; nt < 8; nt++) o[nt][r] *= alpha;
        }

        // P: D-layout -> LDS -> A-layout (wave-private buffer; no barrier needed)
#pragma unroll
        for (int nt = 0; nt < 2; nt++)
#pragma unroll
            for (int r = 0; r < 4; r++)
                Pb[wave][quad * 4 + r][nt * 16 + l16] = (bf16)s[nt][r];

        bf16x8 pf = *(const bf16x8*)&Pb[wave][l16][quad * 8];
#pragma unroll
        for (int nt = 0; nt < 8; nt++) {
            bf16x8 vf = *(const bf16x8*)&Vt[nt * 16 + l16][quad * 8];
            o[nt] = __builtin_amdgcn_mfma_f32_16x16x32_bf16(pf, vf, o[nt], 0, 0, 0);
        }
    }

#pragma unroll
    for (int r = 0; r < 4; r++) {
        float inv = 1.0f / lrow[r];
        int row = n0 + wave * 16 + quad * 4 + r;
        bf16* dst = attn_out + (size_t)(b * N_ + row) * C_ + head * HD_;
#pragma unroll
        for (int nt = 0; nt < 8; nt++)
            dst[nt * 16 + l16] = (bf16)(o[nt][r] * inv);
    }
}

// ---------------------------------------------------------------------------
extern "C" void kernel_launch(void* const* d_in, const int* in_sizes, int n_in,
                              void* d_out, int out_size, void* d_ws, size_t ws_size,
                              hipStream_t stream) {
    const float* x      = (const float*)d_in[0];
    const float* w_qkv  = (const float*)d_in[1];
    const float* w_proj = (const float*)d_in[2];
    const float* b_proj = (const float*)d_in[3];
    const float* w_main = (const float*)d_in[4];
    const float* w_rest = (const float*)d_in[5];
    float* out = (float*)d_out;

    // ws layout (shorts): qkv 12.58M | xb 4.19M | wqb 0.79M | wpb 0.26M  (~35.7 MB)
    bf16* qkv  = (bf16*)d_ws;                          // [8192,1536]
    bf16* xb   = qkv + (size_t)BN_ * QKVC_;            // [8192,512]
    bf16* wqb  = xb + (size_t)BN_ * C_;                // [1536,512]
    bf16* wpb  = wqb + 3 * C_ * C_;                    // [512,512]
    bf16* attn = xb;   // xb dead after qkv_gemm -> reuse for attn_out [8192,512]

    cvt_bf16<<<2560, 256, 0, stream>>>(x, xb, w_qkv, wqb, w_proj, wpb);
    gemm_bt<128, QKVC_, false><<<dim3(64, 12), 256, 0, stream>>>(xb, wqb, nullptr, qkv);
    flash_attn<<<dim3(N_ / 64, H_, B_), 256, 0, stream>>>(qkv, w_main, w_rest, attn);
    gemm_bt<64, C_, true><<<dim3(64, 8), 256, 0, stream>>>(attn, wpb, b_proj, out);
}

// Round 4
// 211.024 us; speedup vs baseline: 1.0915x; 1.0101x over previous
//
#include <hip/hip_runtime.h>
#include <hip/hip_bf16.h>

#define B_    8
#define N_    1024
#define C_    512
#define H_    4
#define HD_   128
#define BN_   (B_ * N_)      // 8192
#define QKVC_ 1536
#define SCALE_ 0.08838834764831845f  // 128^-0.5

typedef __bf16 bf16;
typedef __bf16 bf16x8 __attribute__((ext_vector_type(8)));
typedef float  floatx4 __attribute__((ext_vector_type(4)));

__device__ __forceinline__ void gload_lds16(const bf16* g, bf16* l) {
    __builtin_amdgcn_global_load_lds(
        (const __attribute__((address_space(1))) void*)g,
        (__attribute__((address_space(3))) void*)l, 16, 0, 0);
}

// ---------------------------------------------------------------------------
// Kernel 0: fp32 -> bf16 conversion for x, w_qkv, w_proj.
// ---------------------------------------------------------------------------
__global__ __launch_bounds__(256) void cvt_bf16(const float* __restrict__ x,  bf16* __restrict__ xb,
                                                const float* __restrict__ wq, bf16* __restrict__ wqb,
                                                const float* __restrict__ wp, bf16* __restrict__ wpb) {
    int id = blockIdx.x * 256 + threadIdx.x;
    const float* s; bf16* d; int off;
    if (id < 524288)      { s = x;  d = xb;  off = id; }
    else if (id < 622592) { s = wq; d = wqb; off = id - 524288; }
    else                  { s = wp; d = wpb; off = id - 622592; }
    const float4* sp = (const float4*)s + (size_t)off * 2;
    float4 f0 = sp[0], f1 = sp[1];
    bf16x8 v;
    v[0] = (bf16)f0.x; v[1] = (bf16)f0.y; v[2] = (bf16)f0.z; v[3] = (bf16)f0.w;
    v[4] = (bf16)f1.x; v[5] = (bf16)f1.y; v[6] = (bf16)f1.z; v[7] = (bf16)f1.w;
    ((bf16x8*)d)[off] = v;
}

// ---------------------------------------------------------------------------
// m97-class GEMM: C[m][n] = sum_k A[m][k]*Bw[n][k] (+bias), bf16 in.
// LDS tiles [rows][64] unpadded, XOR chunk swizzle (chunk c of row r at
// c^(r&7)) -> global_load_lds-compatible and b128-read conflict-free.
// ---------------------------------------------------------------------------
template<int TN, int NOUT, bool F32OUT>
__global__ __launch_bounds__(256) void gemm_bt(const bf16* __restrict__ A,
                                               const bf16* __restrict__ Bw,
                                               const float* __restrict__ bias,
                                               void* __restrict__ Cout) {
    constexpr int NT = TN / 32;
    const int t = threadIdx.x;
    const int wave = t >> 6, lane = t & 63;
    const int quad = lane >> 4, l16 = lane & 15;
    const int ro = lane >> 3;
    const int ch = (lane & 7) ^ ro;

    const int m_base = blockIdx.x * 128;
    const int n_base = blockIdx.y * TN;
    const int wave_r = (wave & 1) * 64;
    const int wave_c = (wave >> 1) * (TN / 2);

    __shared__ bf16 As[128 * 64];
    __shared__ bf16 Bs[TN * 64];

    floatx4 acc[4][NT] = {};

    for (int k0 = 0; k0 < 512; k0 += 64) {
        __syncthreads();
#pragma unroll
        for (int j = 0; j < 4; j++) {
            int r0 = (wave * 4 + j) * 8;
            gload_lds16(A + (size_t)(m_base + r0 + ro) * 512 + k0 + ch * 8,
                        As + r0 * 64);
        }
#pragma unroll
        for (int j = 0; j < TN / 32; j++) {
            int r0 = (wave * (TN / 32) + j) * 8;
            gload_lds16(Bw + (size_t)(n_base + r0 + ro) * 512 + k0 + ch * 8,
                        Bs + r0 * 64);
        }
        __syncthreads();

#pragma unroll
        for (int kk = 0; kk < 2; kk++) {
            const int kc = kk * 4 + quad;
            bf16x8 af[4], bfr[NT];
#pragma unroll
            for (int mt = 0; mt < 4; mt++) {
                int r = wave_r + mt * 16 + l16;
                af[mt] = *(const bf16x8*)&As[r * 64 + ((kc ^ (r & 7)) * 8)];
            }
#pragma unroll
            for (int nt = 0; nt < NT; nt++) {
                int r = wave_c + nt * 16 + l16;
                bfr[nt] = *(const bf16x8*)&Bs[r * 64 + ((kc ^ (r & 7)) * 8)];
            }
#pragma unroll
            for (int mt = 0; mt < 4; mt++)
#pragma unroll
                for (int nt = 0; nt < NT; nt++)
                    acc[mt][nt] = __builtin_amdgcn_mfma_f32_16x16x32_bf16(
                        af[mt], bfr[nt], acc[mt][nt], 0, 0, 0);
        }
    }

#pragma unroll
    for (int nt = 0; nt < NT; nt++) {
        int col = n_base + wave_c + nt * 16 + l16;
        float bi = 0.f;
        if constexpr (F32OUT) bi = bias[col];
#pragma unroll
        for (int mt = 0; mt < 4; mt++) {
#pragma unroll
            for (int r = 0; r < 4; r++) {
                int row = m_base + wave_r + mt * 16 + quad * 4 + r;
                if constexpr (F32OUT)
                    ((float*)Cout)[(size_t)row * NOUT + col] = acc[mt][nt][r] + bi;
                else
                    ((bf16*)Cout)[(size_t)row * NOUT + col] = (bf16)acc[mt][nt][r];
            }
        }
    }
}

// ---------------------------------------------------------------------------
// Fused CIM flash attention, split-K over sequence (split in {0,1}, 512 keys
// each).  Writes UNNORMALIZED O (bf16) + per-row (m, l) fp32 for the merge.
//   Kt: unpadded [32][512], XOR chunk swizzle, staged via global_load_lds.
//   Vt: [128][40] via register transpose (4B global loads, b128 LDS writes).
//   Row-sums of P via MFMA against a ones-fragment (no shfl-sum).
// ---------------------------------------------------------------------------
__global__ __launch_bounds__(256) void flash_attn(const bf16* __restrict__ qkv,
                                                  const float* __restrict__ w_main,
                                                  const float* __restrict__ w_rest,
                                                  bf16* __restrict__ po,
                                                  float* __restrict__ ml) {
    const int b = blockIdx.z >> 1, split = blockIdx.z & 1;
    const int head = blockIdx.y;
    const int n0 = blockIdx.x * 64;
    const int t = threadIdx.x;
    const int wave = t >> 6, lane = t & 63;
    const int quad = lane >> 4, l16 = lane & 15;

    float qs[H_];
#pragma unroll
    for (int j = 0; j < H_; j++) {
        float mij = (j == head) ? w_main[head]
                                : w_rest[head * (H_ - 1) + (j - (j > head ? 1 : 0))];
        qs[j] = mij * SCALE_;
    }

    __shared__ bf16 Kt[32 * 512];      // 32 KB, XOR-swizzled, unpadded
    __shared__ bf16 Vt[128][40];       // 10.2 KB
    __shared__ bf16 Pb[4][16][40];     // 5.1 KB, per-wave

    // Q' fragments (A-layout), mix+scale folded in
    bf16x8 qf[16];
    const int qrow = n0 + wave * 16 + l16;
    const bf16* qbase = qkv + (size_t)(b * N_ + qrow) * QKVC_;
#pragma unroll
    for (int kk = 0; kk < 16; kk++) {
        int kg = kk * 32 + quad * 8;
        bf16x8 v = *(const bf16x8*)(qbase + kg);
        float sc = qs[kg >> 7];
        bf16x8 q;
#pragma unroll
        for (int j = 0; j < 8; j++) q[j] = (bf16)((float)v[j] * sc);
        qf[kk] = q;
    }

    bf16x8 vones;
#pragma unroll
    for (int j = 0; j < 8; j++) vones[j] = (bf16)1.0f;

    floatx4 o[8] = {};
    float mrow[4] = {-1e30f, -1e30f, -1e30f, -1e30f};
    float lrow[4] = {0.f, 0.f, 0.f, 0.f};

    const bf16* kvbase = qkv + (size_t)(b * N_) * QKVC_;
    const int vg = t & 3, vp = t >> 2;          // V-transpose mapping
    const int m_begin = split * 512;

    for (int m0 = m_begin; m0 < m_begin + 512; m0 += 32) {
        __syncthreads();
        // --- K tile: wave w stages rows 8w..8w+7, one global_load_lds per row
#pragma unroll
        for (int j = 0; j < 8; j++) {
            int r = wave * 8 + j;
            gload_lds16(kvbase + (size_t)(m0 + r) * QKVC_ + 512 + ((lane ^ (r & 7)) << 3),
                        Kt + r * 512);
        }
        // --- V tile: register transpose, rows 8*vg..8*vg+7, d = 2*vp, 2*vp+1
        {
            const bf16* vs = kvbase + (size_t)(m0 + 8 * vg) * QKVC_ + 1024 + head * HD_ + 2 * vp;
            unsigned int dw[8];
#pragma unroll
            for (int j = 0; j < 8; j++)
                dw[j] = *(const unsigned int*)(vs + (size_t)j * QKVC_);
            uint4 lo, hi;
            lo.x = (dw[0] & 0xffffu) | (dw[1] << 16);
            lo.y = (dw[2] & 0xffffu) | (dw[3] << 16);
            lo.z = (dw[4] & 0xffffu) | (dw[5] << 16);
            lo.w = (dw[6] & 0xffffu) | (dw[7] << 16);
            hi.x = (dw[0] >> 16) | (dw[1] & 0xffff0000u);
            hi.y = (dw[2] >> 16) | (dw[3] & 0xffff0000u);
            hi.z = (dw[4] >> 16) | (dw[5] & 0xffff0000u);
            hi.w = (dw[6] >> 16) | (dw[7] & 0xffff0000u);
            *(uint4*)&Vt[2 * vp][8 * vg] = lo;
            *(uint4*)&Vt[2 * vp + 1][8 * vg] = hi;
        }
        __syncthreads();

        // --- Scores: S[16 x 32] = Q'[16 x 512] @ Kcat^T (swizzled reads)
        floatx4 s[2] = {};
#pragma unroll
        for (int kk = 0; kk < 16; kk++) {
#pragma unroll
            for (int nt = 0; nt < 2; nt++) {
                int r = nt * 16 + l16;
                bf16x8 kb = *(const bf16x8*)&Kt[r * 512 + (((kk * 4 + quad) ^ (r & 7)) << 3)];
                s[nt] = __builtin_amdgcn_mfma_f32_16x16x32_bf16(qf[kk], kb, s[nt], 0, 0, 0);
            }
        }

        // --- Online softmax: max via shfl, exp, rescale o/l
#pragma unroll
        for (int r = 0; r < 4; r++) {
            float mx = fmaxf(s[0][r], s[1][r]);
#pragma unroll
            for (int off = 1; off < 16; off <<= 1) mx = fmaxf(mx, __shfl_xor(mx, off));
            float mnew = fmaxf(mrow[r], mx);
            float alpha = __expf(mrow[r] - mnew);
            mrow[r] = mnew;
            s[0][r] = __expf(s[0][r] - mnew);
            s[1][r] = __expf(s[1][r] - mnew);
            lrow[r] *= alpha;
#pragma unroll
            for (int nt = 0; nt < 8; nt++) o[nt][r] *= alpha;
        }

        // --- P: D-layout -> LDS -> A-layout (wave-private, no barrier)
#pragma unroll
        for (int nt = 0; nt < 2; nt++)
#pragma unroll
            for (int r = 0; r < 4; r++)
                Pb[wave][quad * 4 + r][nt * 16 + l16] = (bf16)s[nt][r];

        bf16x8 pf = *(const bf16x8*)&Pb[wave][l16][quad * 8];

        // --- Row sums of P via MFMA vs ones (l update)
        floatx4 s9 = __builtin_amdgcn_mfma_f32_16x16x32_bf16(
            pf, vones, (floatx4){0.f, 0.f, 0.f, 0.f}, 0, 0, 0);
#pragma unroll
        for (int r = 0; r < 4; r++) lrow[r] += s9[r];

        // --- O += P @ V
#pragma unroll
        for (int nt = 0; nt < 8; nt++) {
            bf16x8 vf = *(const bf16x8*)&Vt[nt * 16 + l16][quad * 8];
            o[nt] = __builtin_amdgcn_mfma_f32_16x16x32_bf16(pf, vf, o[nt], 0, 0, 0);
        }
    }

    // --- Epilogue: store unnormalized O + (m,l)
    bf16* pod = po + (size_t)split * BN_ * C_;
#pragma unroll
    for (int r = 0; r < 4; r++) {
        int row = n0 + wave * 16 + quad * 4 + r;
        bf16* dst = pod + (size_t)(b * N_ + row) * C_ + head * HD_;
#pragma unroll
        for (int nt = 0; nt < 8; nt++)
            dst[nt * 16 + l16] = (bf16)o[nt][r];
        if (l16 == 0) {
            size_t idx = ((size_t)split * BN_ + b * N_ + row) * H_ + head;
            ml[idx * 2]     = mrow[r];
            ml[idx * 2 + 1] = lrow[r];
        }
    }
}

// ---------------------------------------------------------------------------
// Merge the two splits: out = (e0*O0 + e1*O1) / (e0*l0 + e1*l1)
// ---------------------------------------------------------------------------
__global__ __launch_bounds__(256) void merge_splits(const bf16* __restrict__ po,
                                                    const float* __restrict__ ml,
                                                    bf16* __restrict__ attn) {
    int id = blockIdx.x * 256 + threadIdx.x;     // 524288 threads
    int rh = id >> 4;                            // (b*N+row)*H + head, 0..32767
    int d0 = (id & 15) * 8;
    int row = rh >> 2, h = rh & 3;

    float m0v = ml[(size_t)rh * 2],           l0 = ml[(size_t)rh * 2 + 1];
    float m1v = ml[(size_t)(BN_ * H_ + rh) * 2], l1 = ml[(size_t)(BN_ * H_ + rh) * 2 + 1];
    float ms = fmaxf(m0v, m1v);
    float e0 = __expf(m0v - ms), e1 = __expf(m1v - ms);
    float inv = 1.0f / (e0 * l0 + e1 * l1);
    float w0 = e0 * inv, w1 = e1 * inv;

    size_t off = (size_t)row * C_ + h * HD_ + d0;
    bf16x8 a = *(const bf16x8*)(po + off);
    bf16x8 bq = *(const bf16x8*)(po + (size_t)BN_ * C_ + off);
    bf16x8 ov;
#pragma unroll
    for (int j = 0; j < 8; j++)
        ov[j] = (bf16)((float)a[j] * w0 + (float)bq[j] * w1);
    *(bf16x8*)(attn + off) = ov;
}

// ---------------------------------------------------------------------------
extern "C" void kernel_launch(void* const* d_in, const int* in_sizes, int n_in,
                              void* d_out, int out_size, void* d_ws, size_t ws_size,
                              hipStream_t stream) {
    const float* x      = (const float*)d_in[0];
    const float* w_qkv  = (const float*)d_in[1];
    const float* w_proj = (const float*)d_in[2];
    const float* b_proj = (const float*)d_in[3];
    const float* w_main = (const float*)d_in[4];
    const float* w_rest = (const float*)d_in[5];
    float* out = (float*)d_out;

    // ws layout (shorts): qkv 12.58M | xb 4.19M | wqb 0.79M | wpb 0.26M |
    //                     po 8.39M | ml 0.26M-eq   (~53 MB total)
    bf16* qkv = (bf16*)d_ws;                           // [8192,1536]
    bf16* xb  = qkv + (size_t)BN_ * QKVC_;             // [8192,512]
    bf16* wqb = xb + (size_t)BN_ * C_;                 // [1536,512]
    bf16* wpb = wqb + 3 * C_ * C_;                     // [512,512]
    bf16* po  = wpb + C_ * C_;                         // 2 x [8192,512]
    float* ml = (float*)(po + (size_t)2 * BN_ * C_);   // 2 x [32768][2]
    bf16* attn = xb;  // xb dead after qkv_gemm

    cvt_bf16<<<2560, 256, 0, stream>>>(x, xb, w_qkv, wqb, w_proj, wpb);
    gemm_bt<128, QKVC_, false><<<dim3(64, 12), 256, 0, stream>>>(xb, wqb, nullptr, qkv);
    flash_attn<<<dim3(N_ / 64, H_, B_ * 2), 256, 0, stream>>>(qkv, w_main, w_rest, po, ml);
    merge_splits<<<2048, 256, 0, stream>>>(po, ml, attn);
    gemm_bt<64, C_, true><<<dim3(64, 8), 256, 0, stream>>>(attn, wpb, b_proj, out);
}